// Round 1
// baseline (340.901 us; speedup 1.0000x reference)
//
#include <hip/hip_runtime.h>
#include <stdint.h>

#define HIDDEN 1024
#define INTER  4096
#define NWORDS 64          // INTER / 64
#define ROWS   8192        // 4 * 2048
#define MT     16          // rows per GEMM block

typedef unsigned long long u64;

// ---------------------------------------------------------------------------
// Pack sign bits of hidden_states: bit=1 iff x<0. Layout abits[m][k], k=word.
// One block per row; each wave ballots 64 consecutive elements per iteration.
// ---------------------------------------------------------------------------
__global__ __launch_bounds__(256)
void pack_a_kernel(const float* __restrict__ hs, u64* __restrict__ abits) {
    int m    = blockIdx.x;
    int lane = threadIdx.x & 63;
    int wave = threadIdx.x >> 6;
    const float* row = hs + (size_t)m * INTER;
    for (int w = wave; w < NWORDS; w += 4) {
        float x  = row[w * 64 + lane];
        u64 mask = __ballot(x < 0.0f);
        if (lane == 0) abits[(size_t)m * NWORDS + w] = mask;
    }
}

// ---------------------------------------------------------------------------
// Pack sign bits of W transposed to [k][h] (coalesced in GEMM), and compute
// wscale[h] = mean(|W[h,:]|).
// ---------------------------------------------------------------------------
__global__ __launch_bounds__(256)
void pack_w_kernel(const float* __restrict__ W, u64* __restrict__ wbits_t,
                   float* __restrict__ wscale) {
    int h    = blockIdx.x;
    int lane = threadIdx.x & 63;
    int wave = threadIdx.x >> 6;
    const float* row = W + (size_t)h * INTER;
    float asum = 0.f;
    for (int w = wave; w < NWORDS; w += 4) {
        float x = row[w * 64 + lane];
        asum += fabsf(x);
        u64 mask = __ballot(x < 0.0f);
        if (lane == 0) wbits_t[w * HIDDEN + h] = mask;
    }
    #pragma unroll
    for (int off = 32; off > 0; off >>= 1) asum += __shfl_down(asum, off);
    __shared__ float red[4];
    if (lane == 0) red[wave] = asum;
    __syncthreads();
    if (threadIdx.x == 0) {
        float total = red[0] + red[1] + red[2] + red[3];
        wscale[h] = total * (1.0f / INTER);
    }
}

// ---------------------------------------------------------------------------
// Binary GEMM + bias + residual + LayerNorm, fused.
// Block = 16 rows x 1024 cols. Thread t owns cols h = 4t..4t+3 for all 16 rows.
// dot = INTER - 2*popc(a ^ w);  val = clip*wscale[h]*dot + b[h] + input[m][h]
// then LayerNorm across the 1024 cols of each row.
// ---------------------------------------------------------------------------
__global__ __launch_bounds__(256)
void gemm_ln_kernel(const u64* __restrict__ abits, const u64* __restrict__ wbits_t,
                    const float* __restrict__ wscale, const float* __restrict__ bias,
                    const float* __restrict__ clipp, const float* __restrict__ input,
                    const float* __restrict__ gamma, const float* __restrict__ beta,
                    float* __restrict__ out) {
    int m0 = blockIdx.x * MT;
    int t  = threadIdx.x;

    __shared__ u64 sA[MT * NWORDS];            // 8 KB
    const u64* ap = abits + (size_t)m0 * NWORDS;
    for (int i = t; i < MT * NWORDS; i += 256) sA[i] = ap[i];
    __syncthreads();

    int h0 = t * 4;
    int acc[MT][4];
    #pragma unroll
    for (int mi = 0; mi < MT; ++mi)
        #pragma unroll
        for (int hh = 0; hh < 4; ++hh) acc[mi][hh] = 0;

    #pragma unroll 2
    for (int k = 0; k < NWORDS; ++k) {
        const u64* wp = wbits_t + (size_t)k * HIDDEN + h0;
        u64 b0 = wp[0];
        u64 b1 = wp[1];
        u64 b2 = wp[2];
        u64 b3 = wp[3];
        #pragma unroll
        for (int mi = 0; mi < MT; ++mi) {
            u64 a = sA[mi * NWORDS + k];       // LDS broadcast (all lanes same addr)
            acc[mi][0] += __popcll(a ^ b0);
            acc[mi][1] += __popcll(a ^ b1);
            acc[mi][2] += __popcll(a ^ b2);
            acc[mi][3] += __popcll(a ^ b3);
        }
    }

    // epilogue scales
    float clip = clipp[0];
    float4 cw = reinterpret_cast<const float4*>(wscale)[t];
    cw.x *= clip; cw.y *= clip; cw.z *= clip; cw.w *= clip;
    float4 bi = reinterpret_cast<const float4*>(bias)[t];
    float4 gm = reinterpret_cast<const float4*>(gamma)[t];
    float4 bt = reinterpret_cast<const float4*>(beta)[t];

    float vals[MT][4];
    #pragma unroll
    for (int mi = 0; mi < MT; ++mi) {
        float4 inp = reinterpret_cast<const float4*>(input + (size_t)(m0 + mi) * HIDDEN)[t];
        vals[mi][0] = fmaf((float)(INTER - 2 * acc[mi][0]), cw.x, bi.x + inp.x);
        vals[mi][1] = fmaf((float)(INTER - 2 * acc[mi][1]), cw.y, bi.y + inp.y);
        vals[mi][2] = fmaf((float)(INTER - 2 * acc[mi][2]), cw.z, bi.z + inp.z);
        vals[mi][3] = fmaf((float)(INTER - 2 * acc[mi][3]), cw.w, bi.w + inp.w);
    }

    // per-row sum / sumsq reduction: wave shuffle -> LDS cross-wave
    __shared__ float red_s[4][MT];
    __shared__ float red_q[4][MT];
    __shared__ float s_mu[MT], s_rs[MT];
    int lane = t & 63, wave = t >> 6;
    #pragma unroll
    for (int mi = 0; mi < MT; ++mi) {
        float s = vals[mi][0] + vals[mi][1] + vals[mi][2] + vals[mi][3];
        float q = vals[mi][0] * vals[mi][0] + vals[mi][1] * vals[mi][1]
                + vals[mi][2] * vals[mi][2] + vals[mi][3] * vals[mi][3];
        #pragma unroll
        for (int off = 32; off > 0; off >>= 1) {
            s += __shfl_down(s, off);
            q += __shfl_down(q, off);
        }
        if (lane == 0) { red_s[wave][mi] = s; red_q[wave][mi] = q; }
    }
    __syncthreads();
    if (t < MT) {
        float s = red_s[0][t] + red_s[1][t] + red_s[2][t] + red_s[3][t];
        float q = red_q[0][t] + red_q[1][t] + red_q[2][t] + red_q[3][t];
        float mu  = s * (1.0f / HIDDEN);
        float var = fmaf(-mu, mu, q * (1.0f / HIDDEN));
        s_mu[t] = mu;
        s_rs[t] = rsqrtf(var + 1e-12f);
    }
    __syncthreads();

    #pragma unroll
    for (int mi = 0; mi < MT; ++mi) {
        float mu = s_mu[mi], rs = s_rs[mi];
        float4 o;
        o.x = (vals[mi][0] - mu) * rs * gm.x + bt.x;
        o.y = (vals[mi][1] - mu) * rs * gm.y + bt.y;
        o.z = (vals[mi][2] - mu) * rs * gm.z + bt.z;
        o.w = (vals[mi][3] - mu) * rs * gm.w + bt.w;
        reinterpret_cast<float4*>(out + (size_t)(m0 + mi) * HIDDEN)[t] = o;
    }
}

// ---------------------------------------------------------------------------
extern "C" void kernel_launch(void* const* d_in, const int* in_sizes, int n_in,
                              void* d_out, int out_size, void* d_ws, size_t ws_size,
                              hipStream_t stream) {
    const float* hs    = (const float*)d_in[0];  // [4,2048,4096]
    const float* inp   = (const float*)d_in[1];  // [4,2048,1024]
    const float* W     = (const float*)d_in[2];  // [1024,4096]
    const float* b     = (const float*)d_in[3];  // [1024]
    const float* clip  = (const float*)d_in[4];  // scalar
    const float* gamma = (const float*)d_in[5];  // [1024]
    const float* beta  = (const float*)d_in[6];  // [1024]
    float* out = (float*)d_out;

    u64*   abits  = (u64*)d_ws;                                        // 4 MB
    u64*   wbits  = (u64*)((char*)d_ws + (size_t)ROWS * NWORDS * 8);   // 512 KB
    float* wscale = (float*)((char*)d_ws + (size_t)ROWS * NWORDS * 8
                                         + (size_t)NWORDS * HIDDEN * 8); // 4 KB

    pack_a_kernel<<<ROWS, 256, 0, stream>>>(hs, abits);
    pack_w_kernel<<<HIDDEN, 256, 0, stream>>>(W, wbits, wscale);
    gemm_ln_kernel<<<ROWS / MT, 256, 0, stream>>>(abits, wbits, wscale, b, clip,
                                                  inp, gamma, beta, out);
}

// Round 2
// 333.687 us; speedup vs baseline: 1.0216x; 1.0216x over previous
//
#include <hip/hip_runtime.h>
#include <stdint.h>

#define HIDDEN 1024
#define INTER  4096
#define NWORDS 64          // INTER / 64
#define ROWS   8192        // 4 * 2048
#define MT     8           // rows per GEMM block
#define GBLK   (ROWS / MT) // 1024 gemm blocks

typedef unsigned long long u64;

// ---------------------------------------------------------------------------
// Fused pack kernel.
//  blocks [0, 2048):   pack hidden_states sign bits, transposed layout
//                      abits_t[((m/MT)*NWORDS + k)*MT + (m%MT)]
//                      so a gemm block's 8 A-words per k are contiguous 64B.
//  blocks [2048, 3072): pack W row signs into wbits_t[k*HIDDEN + h] and
//                      compute wscale[h] = mean(|W[h,:]|).
// ---------------------------------------------------------------------------
__global__ __launch_bounds__(256)
void pack_kernel(const float* __restrict__ hs, const float* __restrict__ W,
                 u64* __restrict__ abits_t, u64* __restrict__ wbits_t,
                 float* __restrict__ wscale) {
    int lane = threadIdx.x & 63;
    int wave = threadIdx.x >> 6;
    int b = blockIdx.x;

    if (b < ROWS / 4) {
        // one wave per hidden_states row
        int m = b * 4 + wave;
        const float* row = hs + (size_t)m * INTER;
        u64* dst = abits_t + (size_t)(m >> 3) * NWORDS * MT + (m & 7);
        #pragma unroll 4
        for (int w = 0; w < NWORDS; ++w) {
            float x = row[w * 64 + lane];
            u64 mask = __ballot(x < 0.0f);
            if (lane == 0) dst[(size_t)w * MT] = mask;
        }
    } else {
        // one block per W row
        int h = b - ROWS / 4;
        const float* row = W + (size_t)h * INTER;
        float asum = 0.f;
        for (int w = wave; w < NWORDS; w += 4) {
            float x = row[w * 64 + lane];
            asum += fabsf(x);
            u64 mask = __ballot(x < 0.0f);
            if (lane == 0) wbits_t[(size_t)w * HIDDEN + h] = mask;
        }
        #pragma unroll
        for (int off = 32; off > 0; off >>= 1) asum += __shfl_down(asum, off);
        __shared__ float red[4];
        if (lane == 0) red[wave] = asum;
        __syncthreads();
        if (threadIdx.x == 0)
            wscale[h] = (red[0] + red[1] + red[2] + red[3]) * (1.0f / INTER);
    }
}

// ---------------------------------------------------------------------------
// Binary GEMM + bias + residual + LayerNorm, fused.
// Block = 8 rows x 1024 cols, 256 threads; thread t owns cols h = 4t..4t+3.
// A-words are wave-uniform (contiguous 64B per k) -> scalar loads (SMEM).
// dot = INTER - 2*popc(a ^ w);  val = clip*wscale[h]*dot + b[h] + input[m][h]
// then LayerNorm across the 1024 cols of each row.
// ---------------------------------------------------------------------------
__global__ __launch_bounds__(256, 4)
void gemm_ln_kernel(const u64* __restrict__ abits_t, const u64* __restrict__ wbits_t,
                    const float* __restrict__ wscale, const float* __restrict__ bias,
                    const float* __restrict__ clipp, const float* __restrict__ input,
                    const float* __restrict__ gamma, const float* __restrict__ beta,
                    float* __restrict__ out) {
    int t  = threadIdx.x;
    int m0 = blockIdx.x * MT;
    int h0 = t * 4;
    const u64* ablk = abits_t + (size_t)blockIdx.x * NWORDS * MT;

    int acc[MT][4];
    #pragma unroll
    for (int mi = 0; mi < MT; ++mi)
        #pragma unroll
        for (int c = 0; c < 4; ++c) acc[mi][c] = 0;

    #pragma unroll 2
    for (int k = 0; k < NWORDS; ++k) {
        const u64* wp = wbits_t + (size_t)k * HIDDEN + h0;
        u64 w0 = wp[0];
        u64 w1 = wp[1];
        u64 w2 = wp[2];
        u64 w3 = wp[3];
        const u64* ap = ablk + k * MT;      // wave-uniform address -> s_load
        #pragma unroll
        for (int mi = 0; mi < MT; ++mi) {
            u64 a = ap[mi];
            acc[mi][0] += __popcll(a ^ w0);
            acc[mi][1] += __popcll(a ^ w1);
            acc[mi][2] += __popcll(a ^ w2);
            acc[mi][3] += __popcll(a ^ w3);
        }
    }

    // epilogue scales
    float clip = clipp[0];
    float4 cw = reinterpret_cast<const float4*>(wscale)[t];
    cw.x *= clip; cw.y *= clip; cw.z *= clip; cw.w *= clip;
    float4 bi = reinterpret_cast<const float4*>(bias)[t];
    float4 gm = reinterpret_cast<const float4*>(gamma)[t];
    float4 bt = reinterpret_cast<const float4*>(beta)[t];

    float vals[MT][4];
    #pragma unroll
    for (int mi = 0; mi < MT; ++mi) {
        float4 inp = reinterpret_cast<const float4*>(input + (size_t)(m0 + mi) * HIDDEN)[t];
        vals[mi][0] = fmaf((float)(INTER - 2 * acc[mi][0]), cw.x, bi.x + inp.x);
        vals[mi][1] = fmaf((float)(INTER - 2 * acc[mi][1]), cw.y, bi.y + inp.y);
        vals[mi][2] = fmaf((float)(INTER - 2 * acc[mi][2]), cw.z, bi.z + inp.z);
        vals[mi][3] = fmaf((float)(INTER - 2 * acc[mi][3]), cw.w, bi.w + inp.w);
    }

    // per-row sum / sumsq reduction: wave shuffle -> LDS cross-wave
    __shared__ float red_s[4][MT];
    __shared__ float red_q[4][MT];
    __shared__ float s_mu[MT], s_rs[MT];
    int lane = t & 63, wave = t >> 6;
    #pragma unroll
    for (int mi = 0; mi < MT; ++mi) {
        float s = vals[mi][0] + vals[mi][1] + vals[mi][2] + vals[mi][3];
        float q = vals[mi][0] * vals[mi][0] + vals[mi][1] * vals[mi][1]
                + vals[mi][2] * vals[mi][2] + vals[mi][3] * vals[mi][3];
        #pragma unroll
        for (int off = 32; off > 0; off >>= 1) {
            s += __shfl_down(s, off);
            q += __shfl_down(q, off);
        }
        if (lane == 0) { red_s[wave][mi] = s; red_q[wave][mi] = q; }
    }
    __syncthreads();
    if (t < MT) {
        float s = red_s[0][t] + red_s[1][t] + red_s[2][t] + red_s[3][t];
        float q = red_q[0][t] + red_q[1][t] + red_q[2][t] + red_q[3][t];
        float mu  = s * (1.0f / HIDDEN);
        float var = fmaf(-mu, mu, q * (1.0f / HIDDEN));
        s_mu[t] = mu;
        s_rs[t] = rsqrtf(var + 1e-12f);
    }
    __syncthreads();

    #pragma unroll
    for (int mi = 0; mi < MT; ++mi) {
        float mu = s_mu[mi], rs = s_rs[mi];
        float4 o;
        o.x = (vals[mi][0] - mu) * rs * gm.x + bt.x;
        o.y = (vals[mi][1] - mu) * rs * gm.y + bt.y;
        o.z = (vals[mi][2] - mu) * rs * gm.z + bt.z;
        o.w = (vals[mi][3] - mu) * rs * gm.w + bt.w;
        reinterpret_cast<float4*>(out + (size_t)(m0 + mi) * HIDDEN)[t] = o;
    }
}

// ---------------------------------------------------------------------------
extern "C" void kernel_launch(void* const* d_in, const int* in_sizes, int n_in,
                              void* d_out, int out_size, void* d_ws, size_t ws_size,
                              hipStream_t stream) {
    const float* hs    = (const float*)d_in[0];  // [4,2048,4096]
    const float* inp   = (const float*)d_in[1];  // [4,2048,1024]
    const float* W     = (const float*)d_in[2];  // [1024,4096]
    const float* b     = (const float*)d_in[3];  // [1024]
    const float* clip  = (const float*)d_in[4];  // scalar
    const float* gamma = (const float*)d_in[5];  // [1024]
    const float* beta  = (const float*)d_in[6];  // [1024]
    float* out = (float*)d_out;

    u64*   abits  = (u64*)d_ws;                                        // 4 MB
    u64*   wbits  = (u64*)((char*)d_ws + (size_t)ROWS * NWORDS * 8);   // 512 KB
    float* wscale = (float*)((char*)d_ws + (size_t)ROWS * NWORDS * 8
                                         + (size_t)NWORDS * HIDDEN * 8); // 4 KB

    pack_kernel<<<ROWS / 4 + HIDDEN, 256, 0, stream>>>(hs, W, abits, wbits, wscale);
    gemm_ln_kernel<<<GBLK, 256, 0, stream>>>(abits, wbits, wscale, b, clip,
                                             inp, gamma, beta, out);
}

// Round 3
// 312.072 us; speedup vs baseline: 1.0924x; 1.0693x over previous
//
#include <hip/hip_runtime.h>
#include <stdint.h>

#define HIDDEN 1024
#define INTER  4096
#define NWORDS 64          // INTER / 64 bit-words per row
#define NCHUNK 16          // INTER / 256 pack chunks per row
#define ROWS   8192        // 4 * 2048
#define MT     8           // rows per main block
#define GBLK   (ROWS / MT) // 1024 main blocks

typedef unsigned long long u64;

// Bit-packing convention (shared by A and B — popcount(xor) is invariant
// under any fixed bit permutation, so only consistency matters):
// chunk c = elements [256c, 256c+256); lane l owns float4 at 256c+4l;
// word 4c+j holds ballot of component j across the 64 lanes.

// ---------------------------------------------------------------------------
// Pack W signs into wbits_t[k*HIDDEN + h] and wscale[h] = mean(|W[h,:]|).
// One block per W row.
// ---------------------------------------------------------------------------
__global__ __launch_bounds__(256)
void pack_w_kernel(const float* __restrict__ W, u64* __restrict__ wbits_t,
                   float* __restrict__ wscale) {
    int h    = blockIdx.x;
    int lane = threadIdx.x & 63;
    int wave = threadIdx.x >> 6;
    const float4* row = (const float4*)(W + (size_t)h * INTER);
    float asum = 0.f;
    #pragma unroll
    for (int c = wave; c < NCHUNK; c += 4) {
        float4 v = row[c * 64 + lane];
        asum += fabsf(v.x) + fabsf(v.y) + fabsf(v.z) + fabsf(v.w);
        u64 b0 = __ballot(v.x < 0.0f);
        u64 b1 = __ballot(v.y < 0.0f);
        u64 b2 = __ballot(v.z < 0.0f);
        u64 b3 = __ballot(v.w < 0.0f);
        if (lane == 0) {
            u64* dst = wbits_t + (size_t)(4 * c) * HIDDEN + h;
            dst[0 * HIDDEN] = b0;
            dst[1 * HIDDEN] = b1;
            dst[2 * HIDDEN] = b2;
            dst[3 * HIDDEN] = b3;
        }
    }
    #pragma unroll
    for (int off = 32; off > 0; off >>= 1) asum += __shfl_down(asum, off);
    __shared__ float red[4];
    if (lane == 0) red[wave] = asum;
    __syncthreads();
    if (threadIdx.x == 0)
        wscale[h] = (red[0] + red[1] + red[2] + red[3]) * (1.0f / INTER);
}

// ---------------------------------------------------------------------------
// Fused: pack A signs (8 rows -> 4KB LDS) + binary GEMM + bias + residual
// + LayerNorm. Block = 8 rows x 1024 cols, 256 threads; thread t owns cols
// h = 4t..4t+3. dot = INTER - 2*popc(a ^ w).
// ---------------------------------------------------------------------------
__global__ __launch_bounds__(256, 4)
void main_kernel(const float* __restrict__ hs, const u64* __restrict__ wbits_t,
                 const float* __restrict__ wscale, const float* __restrict__ bias,
                 const float* __restrict__ clipp, const float* __restrict__ input,
                 const float* __restrict__ gamma, const float* __restrict__ beta,
                 float* __restrict__ out) {
    int t    = threadIdx.x;
    int lane = t & 63;
    int wave = t >> 6;
    int m0   = blockIdx.x * MT;

    __shared__ u64 sA[MT][NWORDS];             // 4 KB

    // ---- stage 1: ballot-pack this block's 8 hs rows into LDS ----
    #pragma unroll
    for (int r = 0; r < 2; ++r) {
        int mi = wave * 2 + r;
        const float4* row = (const float4*)(hs + (size_t)(m0 + mi) * INTER);
        #pragma unroll
        for (int c = 0; c < NCHUNK; ++c) {
            float4 v = row[c * 64 + lane];
            u64 b0 = __ballot(v.x < 0.0f);
            u64 b1 = __ballot(v.y < 0.0f);
            u64 b2 = __ballot(v.z < 0.0f);
            u64 b3 = __ballot(v.w < 0.0f);
            if (lane == 0) {
                sA[mi][4 * c + 0] = b0;
                sA[mi][4 * c + 1] = b1;
                sA[mi][4 * c + 2] = b2;
                sA[mi][4 * c + 3] = b3;
            }
        }
    }
    __syncthreads();

    // ---- stage 2: binary GEMM ----
    int h0 = t * 4;
    int acc[MT][4];
    #pragma unroll
    for (int mi = 0; mi < MT; ++mi)
        #pragma unroll
        for (int c = 0; c < 4; ++c) acc[mi][c] = 0;

    #pragma unroll 2
    for (int k = 0; k < NWORDS; ++k) {
        const u64* wp = wbits_t + (size_t)k * HIDDEN + h0;
        ulonglong2 wA = ((const ulonglong2*)wp)[0];   // cols h0, h0+1
        ulonglong2 wB = ((const ulonglong2*)wp)[1];   // cols h0+2, h0+3
        #pragma unroll
        for (int mi = 0; mi < MT; ++mi) {
            u64 a  = sA[mi][k];                       // LDS broadcast
            u64 x0 = a ^ wA.x;
            u64 x1 = a ^ wA.y;
            u64 x2 = a ^ wB.x;
            u64 x3 = a ^ wB.y;
            acc[mi][0] += __popc((uint32_t)x0) + __popc((uint32_t)(x0 >> 32));
            acc[mi][1] += __popc((uint32_t)x1) + __popc((uint32_t)(x1 >> 32));
            acc[mi][2] += __popc((uint32_t)x2) + __popc((uint32_t)(x2 >> 32));
            acc[mi][3] += __popc((uint32_t)x3) + __popc((uint32_t)(x3 >> 32));
        }
    }

    // ---- epilogue: bias + residual + LayerNorm ----
    float clip = clipp[0];
    float4 cw = reinterpret_cast<const float4*>(wscale)[t];
    cw.x *= clip; cw.y *= clip; cw.z *= clip; cw.w *= clip;
    float4 bi = reinterpret_cast<const float4*>(bias)[t];
    float4 gm = reinterpret_cast<const float4*>(gamma)[t];
    float4 bt = reinterpret_cast<const float4*>(beta)[t];

    float vals[MT][4];
    #pragma unroll
    for (int mi = 0; mi < MT; ++mi) {
        float4 inp = reinterpret_cast<const float4*>(input + (size_t)(m0 + mi) * HIDDEN)[t];
        vals[mi][0] = fmaf((float)(INTER - 2 * acc[mi][0]), cw.x, bi.x + inp.x);
        vals[mi][1] = fmaf((float)(INTER - 2 * acc[mi][1]), cw.y, bi.y + inp.y);
        vals[mi][2] = fmaf((float)(INTER - 2 * acc[mi][2]), cw.z, bi.z + inp.z);
        vals[mi][3] = fmaf((float)(INTER - 2 * acc[mi][3]), cw.w, bi.w + inp.w);
    }

    __shared__ float red_s[4][MT];
    __shared__ float red_q[4][MT];
    __shared__ float s_mu[MT], s_rs[MT];
    #pragma unroll
    for (int mi = 0; mi < MT; ++mi) {
        float s = vals[mi][0] + vals[mi][1] + vals[mi][2] + vals[mi][3];
        float q = vals[mi][0] * vals[mi][0] + vals[mi][1] * vals[mi][1]
                + vals[mi][2] * vals[mi][2] + vals[mi][3] * vals[mi][3];
        #pragma unroll
        for (int off = 32; off > 0; off >>= 1) {
            s += __shfl_down(s, off);
            q += __shfl_down(q, off);
        }
        if (lane == 0) { red_s[wave][mi] = s; red_q[wave][mi] = q; }
    }
    __syncthreads();
    if (t < MT) {
        float s = red_s[0][t] + red_s[1][t] + red_s[2][t] + red_s[3][t];
        float q = red_q[0][t] + red_q[1][t] + red_q[2][t] + red_q[3][t];
        float mu  = s * (1.0f / HIDDEN);
        float var = fmaf(-mu, mu, q * (1.0f / HIDDEN));
        s_mu[t] = mu;
        s_rs[t] = rsqrtf(var + 1e-12f);
    }
    __syncthreads();

    #pragma unroll
    for (int mi = 0; mi < MT; ++mi) {
        float mu = s_mu[mi], rs = s_rs[mi];
        float4 o;
        o.x = (vals[mi][0] - mu) * rs * gm.x + bt.x;
        o.y = (vals[mi][1] - mu) * rs * gm.y + bt.y;
        o.z = (vals[mi][2] - mu) * rs * gm.z + bt.z;
        o.w = (vals[mi][3] - mu) * rs * gm.w + bt.w;
        reinterpret_cast<float4*>(out + (size_t)(m0 + mi) * HIDDEN)[t] = o;
    }
}

// ---------------------------------------------------------------------------
extern "C" void kernel_launch(void* const* d_in, const int* in_sizes, int n_in,
                              void* d_out, int out_size, void* d_ws, size_t ws_size,
                              hipStream_t stream) {
    const float* hs    = (const float*)d_in[0];  // [4,2048,4096]
    const float* inp   = (const float*)d_in[1];  // [4,2048,1024]
    const float* W     = (const float*)d_in[2];  // [1024,4096]
    const float* b     = (const float*)d_in[3];  // [1024]
    const float* clip  = (const float*)d_in[4];  // scalar
    const float* gamma = (const float*)d_in[5];  // [1024]
    const float* beta  = (const float*)d_in[6];  // [1024]
    float* out = (float*)d_out;

    u64*   wbits  = (u64*)d_ws;                                      // 512 KB
    float* wscale = (float*)((char*)d_ws + (size_t)NWORDS * HIDDEN * 8); // 4 KB

    pack_w_kernel<<<HIDDEN, 256, 0, stream>>>(W, wbits, wscale);
    main_kernel<<<GBLK, 256, 0, stream>>>(hs, wbits, wscale, b, clip,
                                          inp, gamma, beta, out);
}